// Round 3
// baseline (121.853 us; speedup 1.0000x reference)
//
#include <hip/hip_runtime.h>
#include <math.h>

#define BB 8
#define NN 512
#define DD 512
#define DKK 64
#define NC 192                    // 3*DK
#define PSZ (3 * BB * DKK * NN)   // 786432 floats per full QKV image
#define CHN (BB * DKK * NN)       // 262144 floats per Q (or K or V) image
#define NPART 8                   // split-K partials

// (1/sqrt(64)) * log2(e) : fold softmax scale into exp2 domain
#define T_FACT 0.18033688011112042591999058f

#if defined(__has_builtin)
#if __has_builtin(__builtin_amdgcn_exp2f)
#define EXP2F(x) __builtin_amdgcn_exp2f(x)
#else
#define EXP2F(x) exp2f(x)
#endif
#else
#define EXP2F(x) exp2f(x)
#endif

// -------------------------------------------------------------------------
// Kernel 1: QKV = X(4096x512) @ W(512x192), channel-major partial output
// [z][which][b][c][n]. Split-K: blockIdx.z picks a K-chunk of kSteps*32.
// A staged ROW-MAJOR (conflict-free float4 writes; micro-kernel reads
// float2 per 2-kk step -> broadcast groups, conflict-free).
// grid (64,3,8), kSteps=2 -> 1536 blocks = 24 waves/CU.
// -------------------------------------------------------------------------
__global__ __launch_bounds__(256) void qkv_gemm(const float* __restrict__ X,
                                                const float* __restrict__ W,
                                                float* __restrict__ outp_base,
                                                int kSteps) {
    __shared__ union {
        struct {
            float As[64][36];  // row-major: As[row][kk]  (36: 144B stride, 16B-aligned)
            float Bs[32][68];  // Bs[kk][col]
        } s;
        float Ct[64][68];      // transpose staging for epilogue
    } sm;

    const int tid   = threadIdx.x;
    const int row0  = blockIdx.x * 64;   // 64 rows of (b,n)-flattened X
    const int which = blockIdx.y;        // 0=Q, 1=K, 2=V
    const int c0    = which * 64;
    const int tc    = tid & 15;
    const int tr    = tid >> 4;

    float acc[4][4] = {};

    for (int s = 0; s < kSteps; ++s) {
        const int k0 = (blockIdx.z * kSteps + s) * 32;
        // stage A row-major: As[row][kk] = X[row0+row][k0+kk]  (float4 copy)
        {
            const int f = tid & 7;    // float4 index along k (0..7)
            const int r = tid >> 3;   // 0..31
            #pragma unroll
            for (int rr = 0; rr < 2; ++rr) {
                const int row = r + rr * 32;
                *(float4*)&sm.s.As[row][4 * f] =
                    *(const float4*)(X + (size_t)(row0 + row) * DD + k0 + 4 * f);
            }
        }
        // stage B: Bs[kk][cc] = W[k0+kk][c0+cc]
        {
            const int cc = tid & 63;
            const int kf = tid >> 6;
            #pragma unroll
            for (int kk = kf; kk < 32; kk += 4)
                sm.s.Bs[kk][cc] = W[(size_t)(k0 + kk) * NC + c0 + cc];
        }
        __syncthreads();

        #pragma unroll 4
        for (int kk = 0; kk < 32; kk += 2) {
            float2 a[4];
            #pragma unroll
            for (int i = 0; i < 4; ++i)
                a[i] = *(const float2*)&sm.s.As[4 * tr + i][kk];
            const float4 b0 = *(const float4*)&sm.s.Bs[kk][4 * tc];
            const float4 b1 = *(const float4*)&sm.s.Bs[kk + 1][4 * tc];
            const float b0e[4] = {b0.x, b0.y, b0.z, b0.w};
            const float b1e[4] = {b1.x, b1.y, b1.z, b1.w};
            #pragma unroll
            for (int i = 0; i < 4; ++i) {
                #pragma unroll
                for (int j = 0; j < 4; ++j) {
                    acc[i][j] = fmaf(a[i].x, b0e[j], acc[i][j]);
                    acc[i][j] = fmaf(a[i].y, b1e[j], acc[i][j]);
                }
            }
        }
        __syncthreads();
    }

    // epilogue: transpose through LDS, write [z][which][b][c][n] coalesced
    #pragma unroll
    for (int i = 0; i < 4; ++i)
        #pragma unroll
        for (int j = 0; j < 4; ++j)
            sm.Ct[4 * tc + j][4 * tr + i] = acc[i][j];
    __syncthreads();

    const int b  = row0 >> 9;
    const int n0 = row0 & 511;
    float* outp = outp_base + (size_t)blockIdx.z * PSZ +
                  ((size_t)which * BB * DKK + (size_t)b * DKK) * NN;
    const int fl  = tid & 15;
    const int cl0 = tid >> 4;
    #pragma unroll
    for (int cc = 0; cc < 4; ++cc) {
        const int c_l = cl0 + cc * 16;
        const float4 v = *(const float4*)&sm.Ct[c_l][4 * fl];
        *(float4*)(outp + (size_t)c_l * NN + n0 + 4 * fl) = v;
    }
}

// -------------------------------------------------------------------------
// Kernel 2: per-(b,c) rank-1 softmax attention, split-K partials summed
// inline during staging. 1024 blocks: (channel, n-half), 1 n per thread.
// k,v staged (summed) in LDS; reads are same-address broadcasts (free).
// -------------------------------------------------------------------------
__global__ __launch_bounds__(256) void attn(const float* __restrict__ parts,
                                            float* __restrict__ sa_t,
                                            int npart) {
    __shared__ float kl[NN];
    __shared__ float vl[NN];
    __shared__ float rmax[4], rmin[4];

    const int tid  = threadIdx.x;
    const int bc   = blockIdx.x >> 1;
    const int half = blockIdx.x & 1;
    const size_t chan = (size_t)bc * NN;

    // stage k (tid<128) / v (tid>=128): sum npart partials, one float4 each
    {
        const int slot  = tid & 127;
        const int which = tid >> 7;  // 0=k, 1=v
        const float4* src =
            (const float4*)(parts + (size_t)(which ? 2 : 1) * CHN + chan) + slot;
        float4 s = {0.f, 0.f, 0.f, 0.f};
        for (int p = 0; p < npart; ++p) {
            const float4 x = src[(size_t)p * (PSZ / 4)];
            s.x += x.x; s.y += x.y; s.z += x.z; s.w += x.w;
        }
        if (which) ((float4*)vl)[slot] = s;
        else       ((float4*)kl)[slot] = s;
    }
    __syncthreads();

    float mx = fmaxf(kl[tid], kl[tid + 256]);
    float mn = fminf(kl[tid], kl[tid + 256]);
    #pragma unroll
    for (int off = 32; off > 0; off >>= 1) {
        mx = fmaxf(mx, __shfl_down(mx, off, 64));
        mn = fminf(mn, __shfl_down(mn, off, 64));
    }
    if ((tid & 63) == 0) { rmax[tid >> 6] = mx; rmin[tid >> 6] = mn; }
    __syncthreads();
    const float kmax = fmaxf(fmaxf(rmax[0], rmax[1]), fmaxf(rmax[2], rmax[3]));
    const float kmin = fminf(fminf(rmin[0], rmin[1]), fminf(rmin[2], rmin[3]));

    const int n = half * 256 + tid;
    float q = 0.f;
    for (int p = 0; p < npart; ++p) q += parts[(size_t)p * PSZ + chan + n];
    const float t = q * T_FACT;
    const float M = t > 0.f ? t * kmax : t * kmin;

    float sw = 0.f, sv = 0.f;
    const float4* k4 = (const float4*)kl;
    const float4* v4 = (const float4*)vl;
    #pragma unroll 4
    for (int j = 0; j < NN / 4; ++j) {
        const float4 kk = k4[j];
        const float4 vv = v4[j];
        const float ke[4] = {kk.x, kk.y, kk.z, kk.w};
        const float ve[4] = {vv.x, vv.y, vv.z, vv.w};
        #pragma unroll
        for (int e = 0; e < 4; ++e) {
            const float w = EXP2F(fmaf(t, ke[e], -M));
            sw += w;
            sv = fmaf(w, ve[e], sv);
        }
    }
    sa_t[chan + n] = sv / sw;
}

// -------------------------------------------------------------------------
// Kernel 3: out = SA(4096x64) @ Wo(64x512). sa_t is K-major per b.
// 512 threads/block (8 waves), 64x64 tile, 2x4 micro-tile.
// -------------------------------------------------------------------------
__global__ __launch_bounds__(512) void out_gemm(const float* __restrict__ sa_t,
                                                const float* __restrict__ Wo,
                                                float* __restrict__ out) {
    __shared__ float As[64][68];  // As[c][n_local]
    __shared__ float Bs[64][68];  // Bs[c][d_local]

    const int tid  = threadIdx.x;
    const int row0 = blockIdx.x * 64;
    const int d0   = blockIdx.y * 64;
    const int b    = row0 >> 9;
    const int n0   = row0 & 511;

    #pragma unroll
    for (int ss = 0; ss < 2; ++ss) {
        const int s = tid + ss * 512;
        const int cidx = s >> 4;
        const int f    = s & 15;
        *(float4*)&As[cidx][4 * f] =
            *(const float4*)(sa_t + (size_t)(b * DKK + cidx) * NN + n0 + 4 * f);
        *(float4*)&Bs[cidx][4 * f] =
            *(const float4*)(Wo + (size_t)cidx * DD + d0 + 4 * f);
    }
    __syncthreads();

    const int tc = tid & 15;   // 4 cols
    const int tr = tid >> 4;   // 0..31 -> 2 rows
    float acc[2][4] = {};
    #pragma unroll 8
    for (int k = 0; k < DKK; ++k) {
        const float2 a = *(const float2*)&As[k][2 * tr];
        const float4 bv = *(const float4*)&Bs[k][4 * tc];
        const float av[2] = {a.x, a.y};
        const float be[4] = {bv.x, bv.y, bv.z, bv.w};
        #pragma unroll
        for (int i = 0; i < 2; ++i)
            #pragma unroll
            for (int j = 0; j < 4; ++j)
                acc[i][j] = fmaf(av[i], be[j], acc[i][j]);
    }

    float* op = out + ((size_t)(b * NN + n0)) * DD + d0;
    #pragma unroll
    for (int i = 0; i < 2; ++i) {
        const float4 v = {acc[i][0], acc[i][1], acc[i][2], acc[i][3]};
        *(float4*)(op + (size_t)(2 * tr + i) * DD + 4 * tc) = v;
    }
}

extern "C" void kernel_launch(void* const* d_in, const int* in_sizes, int n_in,
                              void* d_out, int out_size, void* d_ws, size_t ws_size,
                              hipStream_t stream) {
    const float* X    = (const float*)d_in[0];  // (8,512,512)
    const float* Wqkv = (const float*)d_in[1];  // (512,192)
    const float* Wo   = (const float*)d_in[2];  // (64,512)
    float* out = (float*)d_out;                 // (8,512,512)

    int npart = NPART, kSteps = 16 / NPART;
    if (ws_size < (size_t)(NPART * PSZ + CHN) * sizeof(float)) {
        npart = 1;
        kSteps = 16;
    }

    float* parts = (float*)d_ws;                    // npart * 3 MB partials
    float* sa_t  = parts + (size_t)npart * PSZ;     // 1 MB

    qkv_gemm<<<dim3(64, 3, npart), 256, 0, stream>>>(X, Wqkv, parts, kSteps);
    attn<<<dim3(2 * BB * DKK), 256, 0, stream>>>(parts, sa_t, npart);
    out_gemm<<<dim3(64, 8), 512, 0, stream>>>(sa_t, Wo, out);
}